// Round 4
// baseline (480.440 us; speedup 1.0000x reference)
//
#include <hip/hip_runtime.h>

#define IN_DIM 128
#define OUT_DIM 64

typedef __attribute__((address_space(1))) const void gvoid_t;
typedef __attribute__((address_space(3))) void lvoid_t;

// ---- CSR build: counts -> exclusive scan -> scatter ----

__global__ void zero_counts_kernel(int* __restrict__ counts, int P) {
    int i = blockIdx.x * 256 + threadIdx.x;
    if (i < P) counts[i] = 0;
}

__global__ void count_kernel(const int* __restrict__ idx,
                             int* __restrict__ counts, int E) {
    int e = blockIdx.x * 256 + threadIdx.x;
    if (e < E) atomicAdd(&counts[idx[e]], 1);
}

// Single-block exclusive scan over P counts (P ~ 10000). Also zeroes cursor.
__global__ __launch_bounds__(1024) void scan_kernel(
    const int* __restrict__ counts, int* __restrict__ offs,
    int* __restrict__ cursor, int P) {
    __shared__ int part[1024];
    const int t = threadIdx.x;
    const int chunk = (P + 1023) >> 10;
    const int lo = t * chunk;
    const int hi = (lo + chunk < P) ? (lo + chunk) : P;
    int s = 0;
    for (int i = lo; i < hi; ++i) s += counts[i];
    part[t] = s;
    __syncthreads();
    // Hillis-Steele inclusive scan
    for (int d = 1; d < 1024; d <<= 1) {
        int v = (t >= d) ? part[t - d] : 0;
        __syncthreads();
        part[t] += v;
        __syncthreads();
    }
    int base = (t == 0) ? 0 : part[t - 1];   // exclusive base for this chunk
    for (int i = lo; i < hi; ++i) {
        offs[i] = base;
        cursor[i] = 0;
        base += counts[i];
    }
    if (t == 1023) offs[P] = part[1023];     // total == E
}

__global__ void scatter_kernel(const int* __restrict__ idx,
                               const int* __restrict__ offs,
                               int* __restrict__ cursor,
                               int* __restrict__ edge_ids, int E) {
    int e = blockIdx.x * 256 + threadIdx.x;
    if (e < E) {
        int p = idx[e];
        int pos = atomicAdd(&cursor[p], 1);
        edge_ids[offs[p] + pos] = e;
    }
}

// ---- Main: one block per pool entry. W[p] async-staged to LDS once via
// global_load_lds (width=16) with XOR-swizzled SOURCE (LDS dest stays linear
// per m104/m173); reads apply the same XOR so the stride-512B ds_read_b128
// spreads across banks. Edges of the bucket come from the contiguous CSR
// list (no pointer chase); first edge's x load overlaps W staging. ----
__global__ __launch_bounds__(256) void gemv_pool_kernel(
    const float* __restrict__ x,        // [E,128]
    const float* __restrict__ Wpool,    // [P,64,128]
    const float* __restrict__ bpool,    // [P,64]
    float*       __restrict__ out,      // [E,64]
    const int*   __restrict__ offs,     // [P+1]
    const int*   __restrict__ edge_ids) // [E]
{
    __shared__ float Wlds[OUT_DIM * IN_DIM];   // 32 KB, linear [o][col^ (o&7) per float4]
    __shared__ float xs[4][IN_DIM];            // per-wave x staging

    const int p = blockIdx.x;
    const int start = offs[p];
    const int n = offs[p + 1] - start;
    if (n == 0) return;                        // uniform exit, no barriers yet

    const int wave = threadIdx.x >> 6;
    const int lane = threadIdx.x & 63;

    // Async stage W[p]: 32 instructions (8 per wave), each 64 lanes x 16B = 1KB.
    // LDS slot s = (wave*8+j)*64 + lane -> row o = s>>5, col4 i4 = s&31.
    // Content at (o, i4) is W[o][ i4 ^ (o&7) ] (pre-swizzled source).
    const float* Wp = Wpool + (size_t)p * (OUT_DIM * IN_DIM);
    #pragma unroll
    for (int j = 0; j < 8; ++j) {
        const int s  = ((wave << 3) + j) * 64 + lane;
        const int o  = s >> 5;
        const int i4 = s & 31;
        const float* g = Wp + o * IN_DIM + ((i4 ^ (o & 7)) << 2);
        lvoid_t* ldst = (lvoid_t*)((char*)Wlds + (size_t)((wave << 3) + j) * 1024);
        __builtin_amdgcn_global_load_lds((gvoid_t*)g, ldst, 16, 0, 0);
    }

    const float bv = bpool[(size_t)p * OUT_DIM + lane];

    // Prefetch first edge's x before the barrier (hides under W staging).
    const int j0 = wave;
    int e0 = -1;
    if (j0 < n) {
        e0 = edge_ids[start + j0];
        const float2 xv = reinterpret_cast<const float2*>(
            x + (size_t)e0 * IN_DIM)[lane];
        reinterpret_cast<float2*>(xs[wave])[lane] = xv;
    }
    __syncthreads();   // drains vmcnt (W in LDS) + lgkm (x write)

    for (int j = j0; j < n; j += 4) {
        int e;
        if (j == j0) {
            e = e0;
        } else {
            e = edge_ids[start + j];
            const float2 xv = reinterpret_cast<const float2*>(
                x + (size_t)e * IN_DIM)[lane];
            reinterpret_cast<float2*>(xs[wave])[lane] = xv;
            // same-wave LDS ordering: compiler inserts lgkmcnt before reads
        }
        const float4* xrow = reinterpret_cast<const float4*>(xs[wave]);
        float ax = 0.f, ay = 0.f, az = 0.f, aw = 0.f;
        #pragma unroll
        for (int i4 = 0; i4 < 32; ++i4) {
            const float4 w = *reinterpret_cast<const float4*>(
                reinterpret_cast<const char*>(Wlds)
                + (lane << 9) + ((i4 ^ (lane & 7)) << 4));
            const float4 xq = xrow[i4];       // broadcast (same addr all lanes)
            ax += w.x * xq.x;
            ay += w.y * xq.y;
            az += w.z * xq.z;
            aw += w.w * xq.w;
        }
        const float acc = (ax + ay) + (az + aw) + bv;
        out[(size_t)e * OUT_DIM + lane] = fmaxf(acc, 0.f);
    }
}

extern "C" void kernel_launch(void* const* d_in, const int* in_sizes, int n_in,
                              void* d_out, int out_size, void* d_ws, size_t ws_size,
                              hipStream_t stream) {
    const float* x    = (const float*)d_in[0];   // [E,128,1]
    const int*   idx  = (const int*)d_in[1];     // [E]
    const float* W    = (const float*)d_in[2];   // [P,64,128]
    const float* b    = (const float*)d_in[3];   // [P,64,1]
    float* out = (float*)d_out;                  // [E,64,1] fp32

    const int E = in_sizes[1];
    const int P = in_sizes[2] / (OUT_DIM * IN_DIM);

    int* counts   = (int*)d_ws;          // P
    int* offs     = counts + P;          // P+1
    int* cursor   = offs + P + 1;        // P
    int* edge_ids = cursor + P;          // E

    zero_counts_kernel<<<(P + 255) / 256, 256, 0, stream>>>(counts, P);
    count_kernel<<<(E + 255) / 256, 256, 0, stream>>>(idx, counts, E);
    scan_kernel<<<1, 1024, 0, stream>>>(counts, offs, cursor, P);
    scatter_kernel<<<(E + 255) / 256, 256, 0, stream>>>(idx, offs, cursor, edge_ids, E);
    gemv_pool_kernel<<<P, 256, 0, stream>>>(x, W, b, out, offs, edge_ids);
}

// Round 5
// 461.010 us; speedup vs baseline: 1.0421x; 1.0421x over previous
//
#include <hip/hip_runtime.h>

#define IN_DIM 128
#define OUT_DIM 64
#define MAXCHUNK 64

typedef __attribute__((address_space(1))) const void gvoid_t;
typedef __attribute__((address_space(3))) void lvoid_t;

// ---- Build per-pool linked lists. head[] pre-set to -1 via hipMemsetAsync(0xFF). ----
__global__ void build_lists_kernel(const int* __restrict__ idx,
                                   int* __restrict__ head,
                                   int* __restrict__ nextp, int E) {
    int e = blockIdx.x * 256 + threadIdx.x;
    if (e < E) {
        int p = idx[e];
        nextp[e] = atomicExch(&head[p], e);
    }
}

// ---- One block per pool entry p. W[p] async-staged to LDS once via
// global_load_lds width=16 with XOR-swizzled SOURCE (LDS dest linear, per
// m104/m173); compute reads apply the same XOR so each 8-lane group of the
// stride-512B ds_read_b128 covers all 32 banks (proven correct in R4).
// Lane 0 chases the linked list while the 32 staging loads are in flight.
// Per-edge x loads are software-pipelined: next edge's float2 is fetched to
// registers during the current dot product, LDS-written at iteration top. ----
__global__ __launch_bounds__(256) void gemv_pool_kernel(
    const float* __restrict__ x,      // [E,128]
    const float* __restrict__ Wpool,  // [P,64,128]
    const float* __restrict__ bpool,  // [P,64]
    float*       __restrict__ out,    // [E,64]
    const int*   __restrict__ head,
    const int*   __restrict__ nextp)
{
    __shared__ float Wlds[OUT_DIM * IN_DIM];   // 32 KB, row o at byte o*512,
                                               // float4 i4 stored at i4^(o&7)
    __shared__ float xs[4][IN_DIM];            // per-wave x staging (2 KB)
    __shared__ int   elist[MAXCHUNK];
    __shared__ int   ecount;
    __shared__ int   ecur;

    const int p = blockIdx.x;
    const int h = head[p];
    if (h < 0) return;                         // empty bucket, uniform exit

    const int wave = threadIdx.x >> 6;
    const int lane = threadIdx.x & 63;

    // Issue all 32 async W-staging loads first (8 per wave, 1 KB each).
    const float* Wp = Wpool + (size_t)p * (OUT_DIM * IN_DIM);
    #pragma unroll
    for (int j = 0; j < 8; ++j) {
        const int s  = ((wave << 3) + j) * 64 + lane;
        const int o  = s >> 5;
        const int i4 = s & 31;
        const float* g = Wp + o * IN_DIM + ((i4 ^ (o & 7)) << 2);
        lvoid_t* ldst = (lvoid_t*)((char*)Wlds + (size_t)((wave << 3) + j) * 1024);
        __builtin_amdgcn_global_load_lds((gvoid_t*)g, ldst, 16, 0, 0);
    }

    const float bv = bpool[(size_t)p * OUT_DIM + lane];

    // Chase the chain while staging is in flight (~5 dependent L2 loads,
    // hidden under the 32 KB W fetch).
    if (threadIdx.x == 0) {
        int nn = 0, c = h;
        while (c >= 0 && nn < MAXCHUNK) { elist[nn++] = c; c = nextp[c]; }
        ecount = nn;
        ecur = c;
    }
    __syncthreads();   // drains vmcnt (W staged) + elist visible

    while (true) {
        const int n = ecount;
        int e = (wave < n) ? elist[wave] : -1;
        float2 xr = make_float2(0.f, 0.f);
        if (e >= 0)
            xr = reinterpret_cast<const float2*>(x + (size_t)e * IN_DIM)[lane];

        for (int j = wave; j < n; j += 4) {
            // publish current x to this wave's LDS row (wave-private, in-order DS)
            reinterpret_cast<float2*>(xs[wave])[lane] = xr;
            // issue next edge's x load now; latency hides under the dot product
            const int en = (j + 4 < n) ? elist[j + 4] : -1;
            float2 xn = make_float2(0.f, 0.f);
            if (en >= 0)
                xn = reinterpret_cast<const float2*>(x + (size_t)en * IN_DIM)[lane];

            const float4* xrow = reinterpret_cast<const float4*>(xs[wave]);
            float ax = 0.f, ay = 0.f, az = 0.f, aw = 0.f;
            #pragma unroll
            for (int i4 = 0; i4 < 32; ++i4) {
                const float4 w = *reinterpret_cast<const float4*>(
                    reinterpret_cast<const char*>(Wlds)
                    + (lane << 9) + ((i4 ^ (lane & 7)) << 4));
                const float4 xq = xrow[i4];     // broadcast (same addr all lanes)
                ax += w.x * xq.x;
                ay += w.y * xq.y;
                az += w.z * xq.z;
                aw += w.w * xq.w;
            }
            out[(size_t)e * OUT_DIM + lane] = fmaxf((ax + ay) + (az + aw) + bv, 0.f);
            e = en;
            xr = xn;
        }

        if (n < MAXCHUNK) break;               // chain exhausted (uniform)
        __syncthreads();
        if (threadIdx.x == 0) {                // refill next chunk (rare: n>64)
            int nn = 0, c = ecur;
            while (c >= 0 && nn < MAXCHUNK) { elist[nn++] = c; c = nextp[c]; }
            ecount = nn;
            ecur = c;
        }
        __syncthreads();
    }
}

extern "C" void kernel_launch(void* const* d_in, const int* in_sizes, int n_in,
                              void* d_out, int out_size, void* d_ws, size_t ws_size,
                              hipStream_t stream) {
    const float* x    = (const float*)d_in[0];   // [E,128,1]
    const int*   idx  = (const int*)d_in[1];     // [E]
    const float* W    = (const float*)d_in[2];   // [P,64,128]
    const float* b    = (const float*)d_in[3];   // [P,64,1]
    float* out = (float*)d_out;                  // [E,64,1] fp32

    const int E = in_sizes[1];
    const int P = in_sizes[2] / (OUT_DIM * IN_DIM);

    int* head  = (int*)d_ws;                     // P ints
    int* nextp = head + P;                       // E ints

    // head = -1 everywhere: single async memset (0xFF bytes == int -1)
    hipMemsetAsync(head, 0xFF, (size_t)P * sizeof(int), stream);
    build_lists_kernel<<<(E + 255) / 256, 256, 0, stream>>>(idx, head, nextp, E);
    gemv_pool_kernel<<<P, 256, 0, stream>>>(x, W, b, out, head, nextp);
}